// Round 1
// baseline (930.260 us; speedup 1.0000x reference)
//
#include <hip/hip_runtime.h>
#include <hip/hip_bf16.h>

typedef __attribute__((ext_vector_type(8))) short short8;
typedef __attribute__((ext_vector_type(4))) float f32x4;

#define B_  8
#define C0  64
#define T_  12
#define TP  10
#define NN  4000
#define CC  64
#define BT  80
#define EE  16000
#define NTILE 63   // ceil(4000/64)

static __device__ __forceinline__ float bf2f(__hip_bfloat16 h) { return __bfloat162float(h); }
static __device__ __forceinline__ __hip_bfloat16 f2bf(float f) { return __float2bfloat16(f); }

// ---------------- x [B][64][12][N] fp32 -> xT [B][12][N][64] bf16 ----------------
__global__ __launch_bounds__(256) void k_transpose(const float* __restrict__ x,
                                                   __hip_bfloat16* __restrict__ xT) {
  __shared__ __hip_bfloat16 lds[64][72];
  int n0 = blockIdx.x * 64;
  int bt = blockIdx.y; int b = bt / T_, t = bt % T_;
  int tid = threadIdx.x;
#pragma unroll
  for (int i = 0; i < 4; ++i) {
    int vid = tid + i * 256;
    int c = vid >> 4, nv = vid & 15;
    int n = n0 + nv * 4;
    const float* src = x + ((size_t)(b * C0 + c) * T_ + t) * NN;
    float v0 = 0.f, v1 = 0.f, v2 = 0.f, v3 = 0.f;
    if (n + 3 < NN) {
      float4 v = *(const float4*)(src + n);
      v0 = v.x; v1 = v.y; v2 = v.z; v3 = v.w;
    } else {
      if (n     < NN) v0 = src[n];
      if (n + 1 < NN) v1 = src[n + 1];
      if (n + 2 < NN) v2 = src[n + 2];
      if (n + 3 < NN) v3 = src[n + 3];
    }
    lds[nv * 4 + 0][c] = f2bf(v0);
    lds[nv * 4 + 1][c] = f2bf(v1);
    lds[nv * 4 + 2][c] = f2bf(v2);
    lds[nv * 4 + 3][c] = f2bf(v3);
  }
  __syncthreads();
#pragma unroll
  for (int i = 0; i < 2; ++i) {
    int vid = tid + i * 256;
    int nl = vid >> 3, cv = (vid & 7) * 8;
    int n = n0 + nl;
    if (n < NN) {
      short8 v = *(const short8*)(&lds[nl][cv]);
      *(short8*)(xT + ((size_t)(b * T_ + t) * NN + n) * CC + cv) = v;
    }
  }
}

// ------------- pack conv weights: B[k=dt*64+ci][co] -> [kc][nb][lane][8] -------------
__global__ void k_pack_conv_w(const float* __restrict__ Wc, __hip_bfloat16* __restrict__ wpk) {
  int idx = blockIdx.x * 256 + threadIdx.x;
  if (idx >= 6 * 8 * 64) return;
  int lane = idx & 63, nb = (idx >> 6) & 7, kc = idx >> 9;
  int co = nb * 16 + (lane & 15), quad = lane >> 4;
  __hip_bfloat16* dst = wpk + (size_t)idx * 8;
  for (int j = 0; j < 8; ++j) {
    int k = kc * 32 + quad * 8 + j;
    int dt = k >> 6, ci = k & 63;
    dst[j] = f2bf(Wc[((size_t)co * 64 + ci) * 3 + dt]);  // Wconv[co][ci][dt][0]
  }
}

// ---------------- conv (M=n, K=192, N=128 co) + GLU + residual -> Xn bf16 ----------------
__global__ __launch_bounds__(256) void k_conv_glu(const __hip_bfloat16* __restrict__ xT,
                                                  const __hip_bfloat16* __restrict__ wpk,
                                                  const float* __restrict__ bconv,
                                                  const float* __restrict__ x,
                                                  __hip_bfloat16* __restrict__ Xn) {
  int lane = threadIdx.x & 63, wv = threadIdx.x >> 6;
  int ntile = blockIdx.x, bt = blockIdx.y;
  int b = bt / TP, t = bt % TP;
  int quad = lane >> 4;
  int arow = ntile * 64 + wv * 16 + (lane & 15);
  if (arow >= NN) arow = NN - 1;
  f32x4 acc[8] = {};
#pragma unroll
  for (int kc = 0; kc < 6; ++kc) {
    int dt = kc >> 1;
    int cb = (kc & 1) * 32 + quad * 8;
    short8 a = *(const short8*)(xT + ((size_t)(b * T_ + t + dt) * NN + arow) * CC + cb);
#pragma unroll
    for (int nb = 0; nb < 8; ++nb) {
      short8 bf = *(const short8*)(wpk + ((size_t)(kc * 8 + nb) * 64 + lane) * 8);
      acc[nb] = __builtin_amdgcn_mfma_f32_16x16x32_bf16(a, bf, acc[nb], 0, 0, 0);
    }
  }
  int row0 = ntile * 64 + wv * 16 + quad * 4;
  if (row0 >= NN) return;
  int col = lane & 15;
#pragma unroll
  for (int nb = 0; nb < 4; ++nb) {
    int co = nb * 16 + col;
    float4 xin = *(const float4*)(x + ((size_t)(b * C0 + co) * T_ + (t + 2)) * NN + row0);
    float bP = bconv[co], bQ = bconv[co + 64];
    float xi[4] = {xin.x, xin.y, xin.z, xin.w};
#pragma unroll
    for (int i = 0; i < 4; ++i) {
      float pv = acc[nb][i] + bP + xi[i];
      float qv = acc[nb + 4][i] + bQ;
      float s = 1.0f / (1.0f + __expf(-qv));
      Xn[((size_t)bt * NN + row0 + i) * CC + co] = f2bf(pv * s);
    }
  }
}

// ---------------- CSR build ----------------
__global__ void k_count(const int* __restrict__ dst, int* __restrict__ cnt) {
  int i = blockIdx.x * 256 + threadIdx.x;
  if (i < EE) atomicAdd(&cnt[dst[i]], 1);
}

__global__ __launch_bounds__(1024) void k_scan(const int* __restrict__ cnt,
                                               int* __restrict__ row_start,
                                               int* __restrict__ cursor) {
  __shared__ int part[1024];
  int tid = threadIdx.x;
  int base = tid * 4;
  int s = 0;
#pragma unroll
  for (int i = 0; i < 4; ++i) { int idx = base + i; if (idx < NN) s += cnt[idx]; }
  part[tid] = s;
  __syncthreads();
  for (int off = 1; off < 1024; off <<= 1) {
    int v = 0;
    if (tid >= off) v = part[tid - off];
    __syncthreads();
    part[tid] += v;
    __syncthreads();
  }
  int run = (tid > 0) ? part[tid - 1] : 0;
#pragma unroll
  for (int i = 0; i < 4; ++i) {
    int idx = base + i;
    if (idx < NN) { row_start[idx] = run; cursor[idx] = run; run += cnt[idx]; }
  }
  if (tid == 1023) row_start[NN] = run;
}

__global__ void k_scatter(const int* __restrict__ src, const int* __restrict__ dst,
                          const int* __restrict__ ety, const float* __restrict__ w,
                          int* __restrict__ cursor, int* __restrict__ es,
                          float* __restrict__ ew, int* __restrict__ et2) {
  int i = blockIdx.x * 256 + threadIdx.x;
  if (i < EE) {
    int p = atomicAdd(&cursor[dst[i]], 1);
    es[p] = src[i]; ew[p] = w[i]; et2[p] = ety[i];
  }
}

// ---------------- SpMM: one wave per (bt, dst-row), all etypes in one pass ----------------
struct BPtrs { const __hip_bfloat16* p[3]; };
struct BOut  { __hip_bfloat16* p[3]; };

template <int NE>
__global__ __launch_bounds__(256) void k_spmm(BPtrs in, BOut out,
                                              const int* __restrict__ row_start,
                                              const int* __restrict__ es,
                                              const float* __restrict__ ew,
                                              const int* __restrict__ et2) {
  int lane = threadIdx.x & 63, wv = threadIdx.x >> 6;
  int n = blockIdx.x;
  int bt = blockIdx.y * 4 + wv;
  int s0 = row_start[n], s1 = row_start[n + 1];
  float acc[NE];
#pragma unroll
  for (int e = 0; e < NE; ++e) acc[e] = 0.f;
  for (int i = s0; i < s1; ++i) {
    int s = es[i]; float wgt = ew[i]; int ty = et2[i];
    float v = bf2f(in.p[ty][((size_t)bt * NN + s) * CC + lane]);
#pragma unroll
    for (int e = 0; e < NE; ++e)
      if (ty == e) acc[e] += wgt * v;
  }
#pragma unroll
  for (int e = 0; e < NE; ++e)
    out.p[e][((size_t)bt * NN + n) * CC + lane] = f2bf(acc[e]);
}

// ------------- pack cheb weights: kb0 = sum_e(W[e,0]-W[e,2]); kb odd = W[e,1]; even = 2W[e,2]
__global__ void k_pack_gemm_w(const float* __restrict__ W, __hip_bfloat16* __restrict__ wpk,
                              int NE) {
  int total = (1 + 2 * NE) * 2 * 4 * 64;
  int idx = blockIdx.x * 256 + threadIdx.x;
  if (idx >= total) return;
  int lane = idx & 63, nb = (idx >> 6) & 3, kcg = idx >> 8;
  int kb = kcg >> 1, kc2 = kcg & 1;
  int co = nb * 16 + (lane & 15), quad = lane >> 4;
  __hip_bfloat16* dst = wpk + (size_t)idx * 8;
  for (int j = 0; j < 8; ++j) {
    int c = kc2 * 32 + quad * 8 + j;
    float f;
    if (kb == 0) {
      f = 0.f;
      for (int e = 0; e < NE; ++e)
        f += W[(((size_t)e * 3 + 0) * 64 + c) * 64 + co]
           - W[(((size_t)e * 3 + 2) * 64 + c) * 64 + co];
    } else {
      int e = (kb - 1) >> 1;
      if (kb & 1) f =       W[(((size_t)e * 3 + 1) * 64 + c) * 64 + co];
      else        f = 2.f * W[(((size_t)e * 3 + 2) * 64 + c) * 64 + co];
    }
    dst[j] = f2bf(f);
  }
}

// ---------------- fused GEMM over concatenated K-blocks, epilogue writes transposed out ----
struct ZPtrs { const __hip_bfloat16* p[7]; };

template <int NBLK>
__global__ __launch_bounds__(256) void k_gemm(ZPtrs zs, const __hip_bfloat16* __restrict__ wpk,
                                              const float* __restrict__ bias,
                                              float* __restrict__ out, int choff) {
  int lane = threadIdx.x & 63, wv = threadIdx.x >> 6;
  int ntile = blockIdx.x, bt = blockIdx.y;
  int b = bt / TP, t = bt % TP;
  int quad = lane >> 4;
  int arow = ntile * 64 + wv * 16 + (lane & 15);
  if (arow >= NN) arow = NN - 1;
  f32x4 acc[4] = {};
#pragma unroll
  for (int kb = 0; kb < NBLK; ++kb) {
    const __hip_bfloat16* Z = zs.p[kb];
#pragma unroll
    for (int kc2 = 0; kc2 < 2; ++kc2) {
      short8 a = *(const short8*)(Z + ((size_t)bt * NN + arow) * CC + kc2 * 32 + quad * 8);
#pragma unroll
      for (int nb = 0; nb < 4; ++nb) {
        short8 bf = *(const short8*)(wpk + (((size_t)(kb * 2 + kc2) * 4 + nb) * 64 + lane) * 8);
        acc[nb] = __builtin_amdgcn_mfma_f32_16x16x32_bf16(a, bf, acc[nb], 0, 0, 0);
      }
    }
  }
  int row0 = ntile * 64 + wv * 16 + quad * 4;
  if (row0 >= NN) return;
  int col = lane & 15;
#pragma unroll
  for (int nb = 0; nb < 4; ++nb) {
    int c = nb * 16 + col;
    float bb = bias[c];
    float4 v = make_float4(acc[nb][0] + bb, acc[nb][1] + bb, acc[nb][2] + bb, acc[nb][3] + bb);
    *(float4*)(out + ((size_t)(b * 128 + choff + c) * TP + t) * NN + row0) = v;
  }
}

extern "C" void kernel_launch(void* const* d_in, const int* in_sizes, int n_in,
                              void* d_out, int out_size, void* d_ws, size_t ws_size,
                              hipStream_t stream) {
  const float* x      = (const float*)d_in[0];
  const float* Wconv  = (const float*)d_in[1];
  const float* bconv  = (const float*)d_in[2];
  const float* Wh     = (const float*)d_in[3];
  const float* bh     = (const float*)d_in[4];
  const float* Wt     = (const float*)d_in[5];
  const float* bt_    = (const float*)d_in[6];
  const int*   hg_src = (const int*)d_in[7];
  const int*   hg_dst = (const int*)d_in[8];
  const int*   hg_ety = (const int*)d_in[9];
  const float* hg_w   = (const float*)d_in[10];
  const int*   tg_src = (const int*)d_in[11];
  const int*   tg_dst = (const int*)d_in[12];
  const int*   tg_ety = (const int*)d_in[13];
  const float* tg_w   = (const float*)d_in[14];
  float* out = (float*)d_out;

  char* p = (char*)d_ws;
  auto alloc = [&](size_t bytes) {
    char* r = p;
    p += (bytes + 255) & ~(size_t)255;
    return r;
  };
  const size_t ZN = (size_t)BT * NN * CC;  // elements per node-feature buffer
  __hip_bfloat16* Xn    = (__hip_bfloat16*)alloc(ZN * 2);
  __hip_bfloat16* zbase = (__hip_bfloat16*)alloc(6 * ZN * 2);
  __hip_bfloat16* xT    = (__hip_bfloat16*)zbase;  // overlaps Z region: dead before Z written
  __hip_bfloat16* wpkc  = (__hip_bfloat16*)alloc((size_t)6 * 8 * 64 * 8 * 2);
  __hip_bfloat16* wpkg  = (__hip_bfloat16*)alloc((size_t)7 * 2 * 4 * 64 * 8 * 2);
  int*   cnt       = (int*)alloc((size_t)NN * 4);
  int*   row_start = (int*)alloc((size_t)(NN + 1) * 4);
  int*   cursor    = (int*)alloc((size_t)NN * 4);
  int*   es        = (int*)alloc((size_t)EE * 4);
  float* ew        = (float*)alloc((size_t)EE * 4);
  int*   et2       = (int*)alloc((size_t)EE * 4);

  hipLaunchKernelGGL(k_transpose, dim3(NTILE, B_ * T_), dim3(256), 0, stream, x, xT);
  hipLaunchKernelGGL(k_pack_conv_w, dim3(12), dim3(256), 0, stream, Wconv, wpkc);
  hipLaunchKernelGGL(k_conv_glu, dim3(NTILE, BT), dim3(256), 0, stream, xT, wpkc, bconv, x, Xn);

  for (int g = 0; g < 2; ++g) {
    const int*   gsrc = g ? tg_src : hg_src;
    const int*   gdst = g ? tg_dst : hg_dst;
    const int*   gety = g ? tg_ety : hg_ety;
    const float* gw   = g ? tg_w : hg_w;
    const float* W    = g ? Wt : Wh;
    const float* bias = g ? bt_ : bh;
    int NE = g ? 2 : 3;
    int choff = g ? 64 : 0;

    hipMemsetAsync(cnt, 0, (size_t)NN * 4, stream);
    hipLaunchKernelGGL(k_count, dim3((EE + 255) / 256), dim3(256), 0, stream, gdst, cnt);
    hipLaunchKernelGGL(k_scan, dim3(1), dim3(1024), 0, stream, cnt, row_start, cursor);
    hipLaunchKernelGGL(k_scatter, dim3((EE + 255) / 256), dim3(256), 0, stream,
                       gsrc, gdst, gety, gw, cursor, es, ew, et2);

    BPtrs in1; BOut o1;
    for (int e = 0; e < 3; ++e) { in1.p[e] = Xn; o1.p[e] = zbase + (size_t)(2 * e) * ZN; }
    if (NE == 3)
      hipLaunchKernelGGL(k_spmm<3>, dim3(NN, 20), dim3(256), 0, stream, in1, o1, row_start, es, ew, et2);
    else
      hipLaunchKernelGGL(k_spmm<2>, dim3(NN, 20), dim3(256), 0, stream, in1, o1, row_start, es, ew, et2);

    BPtrs in2; BOut o2;
    for (int e = 0; e < 3; ++e) {
      in2.p[e] = zbase + (size_t)(2 * e) * ZN;
      o2.p[e]  = zbase + (size_t)(2 * e + 1) * ZN;
    }
    if (NE == 3)
      hipLaunchKernelGGL(k_spmm<3>, dim3(NN, 20), dim3(256), 0, stream, in2, o2, row_start, es, ew, et2);
    else
      hipLaunchKernelGGL(k_spmm<2>, dim3(NN, 20), dim3(256), 0, stream, in2, o2, row_start, es, ew, et2);

    int total = (1 + 2 * NE) * 2 * 4 * 64;
    hipLaunchKernelGGL(k_pack_gemm_w, dim3((total + 255) / 256), dim3(256), 0, stream, W, wpkg, NE);

    ZPtrs zs;
    zs.p[0] = Xn;
    for (int k = 1; k < 7; ++k) zs.p[k] = zbase + (size_t)(k - 1) * ZN;
    if (NE == 3)
      hipLaunchKernelGGL(k_gemm<7>, dim3(NTILE, BT), dim3(256), 0, stream, zs, wpkg, bias, out, choff);
    else
      hipLaunchKernelGGL(k_gemm<5>, dim3(NTILE, BT), dim3(256), 0, stream, zs, wpkg, bias, out, choff);
  }
}

// Round 2
// 689.547 us; speedup vs baseline: 1.3491x; 1.3491x over previous
//
#include <hip/hip_runtime.h>
#include <hip/hip_bf16.h>

typedef __attribute__((ext_vector_type(8))) short short8;
typedef __attribute__((ext_vector_type(4))) float f32x4;

#define B_  8
#define C0  64
#define T_  12
#define TP  10
#define NN  4000
#define CC  64
#define BT  80
#define EE  16000
#define NTILE 63   // ceil(4000/64)

static __device__ __forceinline__ float bf2f(__hip_bfloat16 h) { return __bfloat162float(h); }
static __device__ __forceinline__ __hip_bfloat16 f2bf(float f) { return __float2bfloat16(f); }

// ---------------- x [B][64][12][N] fp32 -> xT [B][12][N][64] bf16 ----------------
__global__ __launch_bounds__(256) void k_transpose(const float* __restrict__ x,
                                                   __hip_bfloat16* __restrict__ xT) {
  __shared__ __hip_bfloat16 lds[64][72];
  int n0 = blockIdx.x * 64;
  int bt = blockIdx.y; int b = bt / T_, t = bt % T_;
  int tid = threadIdx.x;
#pragma unroll
  for (int i = 0; i < 4; ++i) {
    int vid = tid + i * 256;
    int c = vid >> 4, nv = vid & 15;
    int n = n0 + nv * 4;
    const float* src = x + ((size_t)(b * C0 + c) * T_ + t) * NN;
    float v0 = 0.f, v1 = 0.f, v2 = 0.f, v3 = 0.f;
    if (n + 3 < NN) {
      float4 v = *(const float4*)(src + n);
      v0 = v.x; v1 = v.y; v2 = v.z; v3 = v.w;
    } else {
      if (n     < NN) v0 = src[n];
      if (n + 1 < NN) v1 = src[n + 1];
      if (n + 2 < NN) v2 = src[n + 2];
      if (n + 3 < NN) v3 = src[n + 3];
    }
    lds[nv * 4 + 0][c] = f2bf(v0);
    lds[nv * 4 + 1][c] = f2bf(v1);
    lds[nv * 4 + 2][c] = f2bf(v2);
    lds[nv * 4 + 3][c] = f2bf(v3);
  }
  __syncthreads();
#pragma unroll
  for (int i = 0; i < 2; ++i) {
    int vid = tid + i * 256;
    int nl = vid >> 3, cv = (vid & 7) * 8;
    int n = n0 + nl;
    if (n < NN) {
      short8 v = *(const short8*)(&lds[nl][cv]);
      *(short8*)(xT + ((size_t)(b * T_ + t) * NN + n) * CC + cv) = v;
    }
  }
}

// ------------- pack conv weights: B[k=dt*64+ci][co] -> [kc][nb][lane][8] -------------
__global__ void k_pack_conv_w(const float* __restrict__ Wc, __hip_bfloat16* __restrict__ wpk) {
  int idx = blockIdx.x * 256 + threadIdx.x;
  if (idx >= 6 * 8 * 64) return;
  int lane = idx & 63, nb = (idx >> 6) & 7, kc = idx >> 9;
  int co = nb * 16 + (lane & 15), quad = lane >> 4;
  __hip_bfloat16* dst = wpk + (size_t)idx * 8;
  for (int j = 0; j < 8; ++j) {
    int k = kc * 32 + quad * 8 + j;
    int dt = k >> 6, ci = k & 63;
    dst[j] = f2bf(Wc[((size_t)co * 64 + ci) * 3 + dt]);  // Wconv[co][ci][dt][0]
  }
}

// ---------------- conv (M=n, K=192, N=128 co) + GLU + residual -> Xn bf16 ----------------
__global__ __launch_bounds__(256) void k_conv_glu(const __hip_bfloat16* __restrict__ xT,
                                                  const __hip_bfloat16* __restrict__ wpk,
                                                  const float* __restrict__ bconv,
                                                  __hip_bfloat16* __restrict__ Xn) {
  int lane = threadIdx.x & 63, wv = threadIdx.x >> 6;
  int ntile = blockIdx.x, bt = blockIdx.y;
  int b = bt / TP, t = bt % TP;
  int quad = lane >> 4;
  int arow = ntile * 64 + wv * 16 + (lane & 15);
  if (arow >= NN) arow = NN - 1;
  f32x4 acc[8] = {};
#pragma unroll
  for (int kc = 0; kc < 6; ++kc) {
    int dt = kc >> 1;
    int cb = (kc & 1) * 32 + quad * 8;
    short8 a = *(const short8*)(xT + ((size_t)(b * T_ + t + dt) * NN + arow) * CC + cb);
#pragma unroll
    for (int nb = 0; nb < 8; ++nb) {
      short8 bf = *(const short8*)(wpk + ((size_t)(kc * 8 + nb) * 64 + lane) * 8);
      acc[nb] = __builtin_amdgcn_mfma_f32_16x16x32_bf16(a, bf, acc[nb], 0, 0, 0);
    }
  }
  int row0 = ntile * 64 + wv * 16 + quad * 4;
  if (row0 >= NN) return;
  int col = lane & 15;
  const __hip_bfloat16* xr = xT + ((size_t)(b * T_ + t + 2) * NN) * CC;  // residual slice (bf16, L1-hot)
#pragma unroll
  for (int nb = 0; nb < 4; ++nb) {
    int co = nb * 16 + col;
    float bP = bconv[co], bQ = bconv[co + 64];
#pragma unroll
    for (int i = 0; i < 4; ++i) {
      float xi = bf2f(xr[(size_t)(row0 + i) * CC + co]);
      float pv = acc[nb][i] + bP + xi;
      float qv = acc[nb + 4][i] + bQ;
      float s = 1.0f / (1.0f + __expf(-qv));
      Xn[((size_t)bt * NN + row0 + i) * CC + co] = f2bf(pv * s);
    }
  }
}

// ---------------- CSR build ----------------
__global__ void k_count(const int* __restrict__ dst, int* __restrict__ cnt) {
  int i = blockIdx.x * 256 + threadIdx.x;
  if (i < EE) atomicAdd(&cnt[dst[i]], 1);
}

__global__ __launch_bounds__(1024) void k_scan(const int* __restrict__ cnt,
                                               int* __restrict__ row_start,
                                               int* __restrict__ cursor) {
  __shared__ int part[1024];
  int tid = threadIdx.x;
  int base = tid * 4;
  int s = 0;
#pragma unroll
  for (int i = 0; i < 4; ++i) { int idx = base + i; if (idx < NN) s += cnt[idx]; }
  part[tid] = s;
  __syncthreads();
  for (int off = 1; off < 1024; off <<= 1) {
    int v = 0;
    if (tid >= off) v = part[tid - off];
    __syncthreads();
    part[tid] += v;
    __syncthreads();
  }
  int run = (tid > 0) ? part[tid - 1] : 0;
#pragma unroll
  for (int i = 0; i < 4; ++i) {
    int idx = base + i;
    if (idx < NN) { row_start[idx] = run; cursor[idx] = run; run += cnt[idx]; }
  }
  if (tid == 1023) row_start[NN] = run;
}

__global__ void k_scatter(const int* __restrict__ src, const int* __restrict__ dst,
                          const int* __restrict__ ety, const float* __restrict__ w,
                          int* __restrict__ cursor, int* __restrict__ es,
                          float* __restrict__ ew, int* __restrict__ et2) {
  int i = blockIdx.x * 256 + threadIdx.x;
  if (i < EE) {
    int p = atomicAdd(&cursor[dst[i]], 1);
    es[p] = src[i]; ew[p] = w[i]; et2[p] = ety[i];
  }
}

// ---------------- SpMM: one wave per (dst-row, 8-bt-group); 8 independent gathers/edge ----
struct BPtrs { const __hip_bfloat16* p[3]; };
struct BOut  { __hip_bfloat16* p[3]; };

template <int NE>
__global__ __launch_bounds__(128) void k_spmm(BPtrs in, BOut out,
                                              const int* __restrict__ row_start,
                                              const int* __restrict__ es,
                                              const float* __restrict__ ew,
                                              const int* __restrict__ et2) {
  int lane = threadIdx.x & 63, wv = threadIdx.x >> 6;
  int n = blockIdx.x;
  int btg = blockIdx.y * 2 + wv;      // 0..9
  int bt0 = btg * 8;
  int s0 = row_start[n], s1 = row_start[n + 1];
  float acc[8][NE];
#pragma unroll
  for (int j = 0; j < 8; ++j)
#pragma unroll
    for (int e = 0; e < NE; ++e) acc[j][e] = 0.f;
  for (int i = s0; i < s1; ++i) {
    int s = es[i]; float wgt = ew[i]; int ty = et2[i];
    const __hip_bfloat16* base = in.p[ty] + ((size_t)bt0 * NN + s) * CC + lane;
    float v[8];
#pragma unroll
    for (int j = 0; j < 8; ++j) v[j] = bf2f(base[(size_t)j * NN * CC]);
    float ws[NE];
#pragma unroll
    for (int e = 0; e < NE; ++e) ws[e] = (ty == e) ? wgt : 0.f;
#pragma unroll
    for (int j = 0; j < 8; ++j)
#pragma unroll
      for (int e = 0; e < NE; ++e) acc[j][e] += ws[e] * v[j];
  }
#pragma unroll
  for (int e = 0; e < NE; ++e)
#pragma unroll
    for (int j = 0; j < 8; ++j)
      out.p[e][((size_t)(bt0 + j) * NN + n) * CC + lane] = f2bf(acc[j][e]);
}

// ------------- pack cheb weights: kb0 = sum_e(W[e,0]-W[e,2]); kb odd = W[e,1]; even = 2W[e,2]
__global__ void k_pack_gemm_w(const float* __restrict__ W, __hip_bfloat16* __restrict__ wpk,
                              int NE) {
  int total = (1 + 2 * NE) * 2 * 4 * 64;
  int idx = blockIdx.x * 256 + threadIdx.x;
  if (idx >= total) return;
  int lane = idx & 63, nb = (idx >> 6) & 3, kcg = idx >> 8;
  int kb = kcg >> 1, kc2 = kcg & 1;
  int co = nb * 16 + (lane & 15), quad = lane >> 4;
  __hip_bfloat16* dst = wpk + (size_t)idx * 8;
  for (int j = 0; j < 8; ++j) {
    int c = kc2 * 32 + quad * 8 + j;
    float f;
    if (kb == 0) {
      f = 0.f;
      for (int e = 0; e < NE; ++e)
        f += W[(((size_t)e * 3 + 0) * 64 + c) * 64 + co]
           - W[(((size_t)e * 3 + 2) * 64 + c) * 64 + co];
    } else {
      int e = (kb - 1) >> 1;
      if (kb & 1) f =       W[(((size_t)e * 3 + 1) * 64 + c) * 64 + co];
      else        f = 2.f * W[(((size_t)e * 3 + 2) * 64 + c) * 64 + co];
    }
    dst[j] = f2bf(f);
  }
}

// ---------------- fused GEMM over concatenated K-blocks, epilogue writes transposed out ----
struct ZPtrs { const __hip_bfloat16* p[7]; };

template <int NBLK>
__global__ __launch_bounds__(256) void k_gemm(ZPtrs zs, const __hip_bfloat16* __restrict__ wpk,
                                              const float* __restrict__ bias,
                                              float* __restrict__ out, int choff) {
  int lane = threadIdx.x & 63, wv = threadIdx.x >> 6;
  int ntile = blockIdx.x, bt = blockIdx.y;
  int b = bt / TP, t = bt % TP;
  int quad = lane >> 4;
  int arow = ntile * 64 + wv * 16 + (lane & 15);
  if (arow >= NN) arow = NN - 1;
  f32x4 acc[4] = {};
#pragma unroll
  for (int kb = 0; kb < NBLK; ++kb) {
    const __hip_bfloat16* Z = zs.p[kb];
#pragma unroll
    for (int kc2 = 0; kc2 < 2; ++kc2) {
      short8 a = *(const short8*)(Z + ((size_t)bt * NN + arow) * CC + kc2 * 32 + quad * 8);
#pragma unroll
      for (int nb = 0; nb < 4; ++nb) {
        short8 bf = *(const short8*)(wpk + (((size_t)(kb * 2 + kc2) * 4 + nb) * 64 + lane) * 8);
        acc[nb] = __builtin_amdgcn_mfma_f32_16x16x32_bf16(a, bf, acc[nb], 0, 0, 0);
      }
    }
  }
  int row0 = ntile * 64 + wv * 16 + quad * 4;
  if (row0 >= NN) return;
  int col = lane & 15;
#pragma unroll
  for (int nb = 0; nb < 4; ++nb) {
    int c = nb * 16 + col;
    float bb = bias[c];
    float4 v = make_float4(acc[nb][0] + bb, acc[nb][1] + bb, acc[nb][2] + bb, acc[nb][3] + bb);
    *(float4*)(out + ((size_t)(b * 128 + choff + c) * TP + t) * NN + row0) = v;
  }
}

extern "C" void kernel_launch(void* const* d_in, const int* in_sizes, int n_in,
                              void* d_out, int out_size, void* d_ws, size_t ws_size,
                              hipStream_t stream) {
  const float* x      = (const float*)d_in[0];
  const float* Wconv  = (const float*)d_in[1];
  const float* bconv  = (const float*)d_in[2];
  const float* Wh     = (const float*)d_in[3];
  const float* bh     = (const float*)d_in[4];
  const float* Wt     = (const float*)d_in[5];
  const float* bt_    = (const float*)d_in[6];
  const int*   hg_src = (const int*)d_in[7];
  const int*   hg_dst = (const int*)d_in[8];
  const int*   hg_ety = (const int*)d_in[9];
  const float* hg_w   = (const float*)d_in[10];
  const int*   tg_src = (const int*)d_in[11];
  const int*   tg_dst = (const int*)d_in[12];
  const int*   tg_ety = (const int*)d_in[13];
  const float* tg_w   = (const float*)d_in[14];
  float* out = (float*)d_out;

  char* p = (char*)d_ws;
  auto alloc = [&](size_t bytes) {
    char* r = p;
    p += (bytes + 255) & ~(size_t)255;
    return r;
  };
  const size_t ZN = (size_t)BT * NN * CC;  // elements per node-feature buffer
  __hip_bfloat16* Xn    = (__hip_bfloat16*)alloc(ZN * 2);
  __hip_bfloat16* zbase = (__hip_bfloat16*)alloc(6 * ZN * 2);
  __hip_bfloat16* xT    = (__hip_bfloat16*)alloc((size_t)B_ * T_ * NN * CC * 2);
  __hip_bfloat16* wpkc  = (__hip_bfloat16*)alloc((size_t)6 * 8 * 64 * 8 * 2);
  __hip_bfloat16* wpkg  = (__hip_bfloat16*)alloc((size_t)7 * 2 * 4 * 64 * 8 * 2);
  int*   cnt       = (int*)alloc((size_t)NN * 4);
  int*   row_start = (int*)alloc((size_t)(NN + 1) * 4);
  int*   cursor    = (int*)alloc((size_t)NN * 4);
  int*   es        = (int*)alloc((size_t)EE * 4);
  float* ew        = (float*)alloc((size_t)EE * 4);
  int*   et2       = (int*)alloc((size_t)EE * 4);

  hipLaunchKernelGGL(k_transpose, dim3(NTILE, B_ * T_), dim3(256), 0, stream, x, xT);
  hipLaunchKernelGGL(k_pack_conv_w, dim3(12), dim3(256), 0, stream, Wconv, wpkc);
  hipLaunchKernelGGL(k_conv_glu, dim3(NTILE, BT), dim3(256), 0, stream, xT, wpkc, bconv, Xn);

  for (int g = 0; g < 2; ++g) {
    const int*   gsrc = g ? tg_src : hg_src;
    const int*   gdst = g ? tg_dst : hg_dst;
    const int*   gety = g ? tg_ety : hg_ety;
    const float* gw   = g ? tg_w : hg_w;
    const float* W    = g ? Wt : Wh;
    const float* bias = g ? bt_ : bh;
    int NE = g ? 2 : 3;
    int choff = g ? 64 : 0;

    hipMemsetAsync(cnt, 0, (size_t)NN * 4, stream);
    hipLaunchKernelGGL(k_count, dim3((EE + 255) / 256), dim3(256), 0, stream, gdst, cnt);
    hipLaunchKernelGGL(k_scan, dim3(1), dim3(1024), 0, stream, cnt, row_start, cursor);
    hipLaunchKernelGGL(k_scatter, dim3((EE + 255) / 256), dim3(256), 0, stream,
                       gsrc, gdst, gety, gw, cursor, es, ew, et2);

    BPtrs in1; BOut o1;
    for (int e = 0; e < 3; ++e) { in1.p[e] = Xn; o1.p[e] = zbase + (size_t)(2 * e) * ZN; }
    if (NE == 3)
      hipLaunchKernelGGL(k_spmm<3>, dim3(NN, 5), dim3(128), 0, stream, in1, o1, row_start, es, ew, et2);
    else
      hipLaunchKernelGGL(k_spmm<2>, dim3(NN, 5), dim3(128), 0, stream, in1, o1, row_start, es, ew, et2);

    BPtrs in2; BOut o2;
    for (int e = 0; e < 3; ++e) {
      in2.p[e] = zbase + (size_t)(2 * e) * ZN;
      o2.p[e]  = zbase + (size_t)(2 * e + 1) * ZN;
    }
    if (NE == 3)
      hipLaunchKernelGGL(k_spmm<3>, dim3(NN, 5), dim3(128), 0, stream, in2, o2, row_start, es, ew, et2);
    else
      hipLaunchKernelGGL(k_spmm<2>, dim3(NN, 5), dim3(128), 0, stream, in2, o2, row_start, es, ew, et2);

    int total = (1 + 2 * NE) * 2 * 4 * 64;
    hipLaunchKernelGGL(k_pack_gemm_w, dim3((total + 255) / 256), dim3(256), 0, stream, W, wpkg, NE);

    ZPtrs zs;
    zs.p[0] = Xn;
    for (int k = 1; k < 7; ++k) zs.p[k] = zbase + (size_t)(k - 1) * ZN;
    if (NE == 3)
      hipLaunchKernelGGL(k_gemm<7>, dim3(NTILE, BT), dim3(256), 0, stream, zs, wpkg, bias, out, choff);
    else
      hipLaunchKernelGGL(k_gemm<5>, dim3(NTILE, BT), dim3(256), 0, stream, zs, wpkg, bias, out, choff);
  }
}

// Round 3
// 656.845 us; speedup vs baseline: 1.4163x; 1.0498x over previous
//
#include <hip/hip_runtime.h>
#include <hip/hip_bf16.h>

typedef __attribute__((ext_vector_type(8))) short short8;
typedef __attribute__((ext_vector_type(4))) float f32x4;

#define B_  8
#define C0  64
#define T_  12
#define TP  10
#define NN  4000
#define CC  64
#define BT  80
#define EE  16000
#define NTILE 63    // ceil(4000/64)  (transpose)
#define MTILE 16    // ceil(4000/256) (conv/gemm 256-row blocks)

static __device__ __forceinline__ float bf2f(__hip_bfloat16 h) { return __bfloat162float(h); }
static __device__ __forceinline__ __hip_bfloat16 f2bf(float f) { return __float2bfloat16(f); }

// ---------------- x [B][64][12][N] fp32 -> xT [B][12][N][64] bf16 ----------------
__global__ __launch_bounds__(256) void k_transpose(const float* __restrict__ x,
                                                   __hip_bfloat16* __restrict__ xT) {
  __shared__ __hip_bfloat16 lds[64][72];
  int n0 = blockIdx.x * 64;
  int bt = blockIdx.y; int b = bt / T_, t = bt % T_;
  int tid = threadIdx.x;
#pragma unroll
  for (int i = 0; i < 4; ++i) {
    int vid = tid + i * 256;
    int c = vid >> 4, nv = vid & 15;
    int n = n0 + nv * 4;
    const float* src = x + ((size_t)(b * C0 + c) * T_ + t) * NN;
    float v0 = 0.f, v1 = 0.f, v2 = 0.f, v3 = 0.f;
    if (n + 3 < NN) {
      float4 v = *(const float4*)(src + n);
      v0 = v.x; v1 = v.y; v2 = v.z; v3 = v.w;
    } else {
      if (n     < NN) v0 = src[n];
      if (n + 1 < NN) v1 = src[n + 1];
      if (n + 2 < NN) v2 = src[n + 2];
      if (n + 3 < NN) v3 = src[n + 3];
    }
    lds[nv * 4 + 0][c] = f2bf(v0);
    lds[nv * 4 + 1][c] = f2bf(v1);
    lds[nv * 4 + 2][c] = f2bf(v2);
    lds[nv * 4 + 3][c] = f2bf(v3);
  }
  __syncthreads();
#pragma unroll
  for (int i = 0; i < 2; ++i) {
    int vid = tid + i * 256;
    int nl = vid >> 3, cv = (vid & 7) * 8;
    int n = n0 + nl;
    if (n < NN) {
      short8 v = *(const short8*)(&lds[nl][cv]);
      *(short8*)(xT + ((size_t)(b * T_ + t) * NN + n) * CC + cv) = v;
    }
  }
}

// ------------- pack conv weights: B[k=dt*64+ci][co] -> [seg=kc*8+nb][lane][8] -------------
__global__ void k_pack_conv_w(const float* __restrict__ Wc, __hip_bfloat16* __restrict__ wpk) {
  int idx = blockIdx.x * 256 + threadIdx.x;
  if (idx >= 6 * 8 * 64) return;
  int lane = idx & 63, nb = (idx >> 6) & 7, kc = idx >> 9;
  int co = nb * 16 + (lane & 15), quad = lane >> 4;
  __hip_bfloat16* dst = wpk + (size_t)idx * 8;
  for (int j = 0; j < 8; ++j) {
    int k = kc * 32 + quad * 8 + j;
    int dt = k >> 6, ci = k & 63;
    dst[j] = f2bf(Wc[((size_t)co * 64 + ci) * 3 + dt]);  // Wconv[co][ci][dt][0]
  }
}

// ------- conv (256 rows/block, K=192, 128 co) + GLU + residual -> Xn bf16; B in LDS -------
__global__ __launch_bounds__(256, 2) void k_conv_glu(const __hip_bfloat16* __restrict__ xT,
                                                     const short8* __restrict__ wpk,
                                                     const float* __restrict__ bconv,
                                                     __hip_bfloat16* __restrict__ Xn) {
  __shared__ short8 bsh[48 * 64];  // 48 KB
  int lane = threadIdx.x & 63, wv = threadIdx.x >> 6;
  int base = blockIdx.x * 256, bt = blockIdx.y;
  int b = bt / TP, t = bt % TP;
  int quad = lane >> 4, col = lane & 15;
  for (int s = wv; s < 48; s += 4) bsh[s * 64 + lane] = wpk[s * 64 + lane];
  __syncthreads();
  int arow[4];
#pragma unroll
  for (int rg = 0; rg < 4; ++rg) {
    int r = base + wv * 64 + rg * 16 + col;
    arow[rg] = (r < NN) ? r : NN - 1;
  }
  f32x4 acc[4][8] = {};
#pragma unroll
  for (int kc = 0; kc < 6; ++kc) {
    int dt = kc >> 1;
    int cb = (kc & 1) * 32 + quad * 8;
    const __hip_bfloat16* Zs = xT + ((size_t)(b * T_ + t + dt) * NN) * CC + cb;
    short8 a[4];
#pragma unroll
    for (int rg = 0; rg < 4; ++rg) a[rg] = *(const short8*)(Zs + (size_t)arow[rg] * CC);
#pragma unroll
    for (int nb = 0; nb < 8; ++nb) {
      short8 bf = bsh[(kc * 8 + nb) * 64 + lane];
#pragma unroll
      for (int rg = 0; rg < 4; ++rg)
        acc[rg][nb] = __builtin_amdgcn_mfma_f32_16x16x32_bf16(a[rg], bf, acc[rg][nb], 0, 0, 0);
    }
  }
  const __hip_bfloat16* xr = xT + ((size_t)(b * T_ + t + 2) * NN) * CC;  // residual (L1/L2-hot)
#pragma unroll
  for (int rg = 0; rg < 4; ++rg) {
    int row0 = base + wv * 64 + rg * 16 + quad * 4;
    if (row0 >= NN) continue;
#pragma unroll
    for (int nb = 0; nb < 4; ++nb) {
      int co = nb * 16 + col;
      float bP = bconv[co], bQ = bconv[co + 64];
#pragma unroll
      for (int i = 0; i < 4; ++i) {
        float xi = bf2f(xr[(size_t)(row0 + i) * CC + co]);
        float pv = acc[rg][nb][i] + bP + xi;
        float qv = acc[rg][nb + 4][i] + bQ;
        float s = 1.0f / (1.0f + __expf(-qv));
        Xn[((size_t)bt * NN + row0 + i) * CC + co] = f2bf(pv * s);
      }
    }
  }
}

// ---------------- CSR build ----------------
__global__ void k_count(const int* __restrict__ dst, int* __restrict__ cnt) {
  int i = blockIdx.x * 256 + threadIdx.x;
  if (i < EE) atomicAdd(&cnt[dst[i]], 1);
}

__global__ __launch_bounds__(1024) void k_scan(const int* __restrict__ cnt,
                                               int* __restrict__ row_start,
                                               int* __restrict__ cursor) {
  __shared__ int part[1024];
  int tid = threadIdx.x;
  int base = tid * 4;
  int s = 0;
#pragma unroll
  for (int i = 0; i < 4; ++i) { int idx = base + i; if (idx < NN) s += cnt[idx]; }
  part[tid] = s;
  __syncthreads();
  for (int off = 1; off < 1024; off <<= 1) {
    int v = 0;
    if (tid >= off) v = part[tid - off];
    __syncthreads();
    part[tid] += v;
    __syncthreads();
  }
  int run = (tid > 0) ? part[tid - 1] : 0;
#pragma unroll
  for (int i = 0; i < 4; ++i) {
    int idx = base + i;
    if (idx < NN) { row_start[idx] = run; cursor[idx] = run; run += cnt[idx]; }
  }
  if (tid == 1023) row_start[NN] = run;
}

__global__ void k_scatter(const int* __restrict__ src, const int* __restrict__ dst,
                          const int* __restrict__ ety, const float* __restrict__ w,
                          int* __restrict__ cursor, int* __restrict__ es,
                          float* __restrict__ ew, int* __restrict__ et2) {
  int i = blockIdx.x * 256 + threadIdx.x;
  if (i < EE) {
    int p = atomicAdd(&cursor[dst[i]], 1);
    es[p] = src[i]; ew[p] = w[i]; et2[p] = ety[i];
  }
}

// ---------------- SpMM: one wave per (dst-row, 8-bt-group); 8 independent gathers/edge ----
struct BPtrs { const __hip_bfloat16* p[3]; };
struct BOut  { __hip_bfloat16* p[3]; };

template <int NE>
__global__ __launch_bounds__(128) void k_spmm(BPtrs in, BOut out,
                                              const int* __restrict__ row_start,
                                              const int* __restrict__ es,
                                              const float* __restrict__ ew,
                                              const int* __restrict__ et2) {
  int lane = threadIdx.x & 63, wv = threadIdx.x >> 6;
  int n = blockIdx.x;
  int btg = blockIdx.y * 2 + wv;      // 0..9
  int bt0 = btg * 8;
  int s0 = row_start[n], s1 = row_start[n + 1];
  float acc[8][NE];
#pragma unroll
  for (int j = 0; j < 8; ++j)
#pragma unroll
    for (int e = 0; e < NE; ++e) acc[j][e] = 0.f;
  for (int i = s0; i < s1; ++i) {
    int s = es[i]; float wgt = ew[i]; int ty = et2[i];
    const __hip_bfloat16* base = in.p[ty] + ((size_t)bt0 * NN + s) * CC + lane;
    float v[8];
#pragma unroll
    for (int j = 0; j < 8; ++j) v[j] = bf2f(base[(size_t)j * NN * CC]);
    float ws[NE];
#pragma unroll
    for (int e = 0; e < NE; ++e) ws[e] = (ty == e) ? wgt : 0.f;
#pragma unroll
    for (int j = 0; j < 8; ++j)
#pragma unroll
      for (int e = 0; e < NE; ++e) acc[j][e] += ws[e] * v[j];
  }
#pragma unroll
  for (int e = 0; e < NE; ++e)
#pragma unroll
    for (int j = 0; j < 8; ++j)
      out.p[e][((size_t)(bt0 + j) * NN + n) * CC + lane] = f2bf(acc[j][e]);
}

// ------------- pack cheb weights: kb0 = sum_e(W[e,0]-W[e,2]); kb odd = W[e,1]; even = 2W[e,2]
__global__ void k_pack_gemm_w(const float* __restrict__ W, __hip_bfloat16* __restrict__ wpk,
                              int NE) {
  int total = (1 + 2 * NE) * 2 * 4 * 64;
  int idx = blockIdx.x * 256 + threadIdx.x;
  if (idx >= total) return;
  int lane = idx & 63, nb = (idx >> 6) & 3, kcg = idx >> 8;
  int kb = kcg >> 1, kc2 = kcg & 1;
  int co = nb * 16 + (lane & 15), quad = lane >> 4;
  __hip_bfloat16* dst = wpk + (size_t)idx * 8;
  for (int j = 0; j < 8; ++j) {
    int c = kc2 * 32 + quad * 8 + j;
    float f;
    if (kb == 0) {
      f = 0.f;
      for (int e = 0; e < NE; ++e)
        f += W[(((size_t)e * 3 + 0) * 64 + c) * 64 + co]
           - W[(((size_t)e * 3 + 2) * 64 + c) * 64 + co];
    } else {
      int e = (kb - 1) >> 1;
      if (kb & 1) f =       W[(((size_t)e * 3 + 1) * 64 + c) * 64 + co];
      else        f = 2.f * W[(((size_t)e * 3 + 2) * 64 + c) * 64 + co];
    }
    dst[j] = f2bf(f);
  }
}

// ------- fused GEMM, 256 rows/block, B staged in LDS, epilogue writes transposed out -------
struct ZPtrs { const __hip_bfloat16* p[7]; };

template <int NBLK>
__global__ __launch_bounds__(256, 2) void k_gemm(ZPtrs zs, const short8* __restrict__ wpk,
                                                 const float* __restrict__ bias,
                                                 float* __restrict__ out, int choff) {
  __shared__ short8 bsh[NBLK * 8 * 64];  // NBLK=7: 57344 B
  int lane = threadIdx.x & 63, wv = threadIdx.x >> 6;
  int base = blockIdx.x * 256, bt = blockIdx.y;
  int b = bt / TP, t = bt % TP;
  int quad = lane >> 4, col = lane & 15;
  for (int s = wv; s < NBLK * 8; s += 4) bsh[s * 64 + lane] = wpk[s * 64 + lane];
  __syncthreads();
  int arow[4];
#pragma unroll
  for (int rg = 0; rg < 4; ++rg) {
    int r = base + wv * 64 + rg * 16 + col;
    arow[rg] = (r < NN) ? r : NN - 1;
  }
  f32x4 acc[4][4] = {};
#pragma unroll
  for (int kb = 0; kb < NBLK; ++kb) {
    const __hip_bfloat16* Z = zs.p[kb] + (size_t)bt * NN * CC;
#pragma unroll
    for (int kc2 = 0; kc2 < 2; ++kc2) {
      int cb = kc2 * 32 + quad * 8;
      short8 a[4];
#pragma unroll
      for (int rg = 0; rg < 4; ++rg) a[rg] = *(const short8*)(Z + (size_t)arow[rg] * CC + cb);
#pragma unroll
      for (int nb = 0; nb < 4; ++nb) {
        short8 bf = bsh[((kb * 2 + kc2) * 4 + nb) * 64 + lane];
#pragma unroll
        for (int rg = 0; rg < 4; ++rg)
          acc[rg][nb] = __builtin_amdgcn_mfma_f32_16x16x32_bf16(a[rg], bf, acc[rg][nb], 0, 0, 0);
      }
    }
  }
#pragma unroll
  for (int rg = 0; rg < 4; ++rg) {
    int row0 = base + wv * 64 + rg * 16 + quad * 4;
    if (row0 >= NN) continue;
#pragma unroll
    for (int nb = 0; nb < 4; ++nb) {
      int c = nb * 16 + col;
      float bb = bias[c];
      float4 v = make_float4(acc[rg][nb][0] + bb, acc[rg][nb][1] + bb,
                             acc[rg][nb][2] + bb, acc[rg][nb][3] + bb);
      *(float4*)(out + ((size_t)(b * 128 + choff + c) * TP + t) * NN + row0) = v;
    }
  }
}

extern "C" void kernel_launch(void* const* d_in, const int* in_sizes, int n_in,
                              void* d_out, int out_size, void* d_ws, size_t ws_size,
                              hipStream_t stream) {
  const float* x      = (const float*)d_in[0];
  const float* Wconv  = (const float*)d_in[1];
  const float* bconv  = (const float*)d_in[2];
  const float* Wh     = (const float*)d_in[3];
  const float* bh     = (const float*)d_in[4];
  const float* Wt     = (const float*)d_in[5];
  const float* bt_    = (const float*)d_in[6];
  const int*   hg_src = (const int*)d_in[7];
  const int*   hg_dst = (const int*)d_in[8];
  const int*   hg_ety = (const int*)d_in[9];
  const float* hg_w   = (const float*)d_in[10];
  const int*   tg_src = (const int*)d_in[11];
  const int*   tg_dst = (const int*)d_in[12];
  const int*   tg_ety = (const int*)d_in[13];
  const float* tg_w   = (const float*)d_in[14];
  float* out = (float*)d_out;

  char* p = (char*)d_ws;
  auto alloc = [&](size_t bytes) {
    char* r = p;
    p += (bytes + 255) & ~(size_t)255;
    return r;
  };
  const size_t ZN = (size_t)BT * NN * CC;  // elements per node-feature buffer
  __hip_bfloat16* Xn    = (__hip_bfloat16*)alloc(ZN * 2);
  __hip_bfloat16* zbase = (__hip_bfloat16*)alloc(6 * ZN * 2);
  __hip_bfloat16* xT    = (__hip_bfloat16*)alloc((size_t)B_ * T_ * NN * CC * 2);
  __hip_bfloat16* wpkc  = (__hip_bfloat16*)alloc((size_t)6 * 8 * 64 * 8 * 2);
  __hip_bfloat16* wpkg  = (__hip_bfloat16*)alloc((size_t)7 * 2 * 4 * 64 * 8 * 2);
  int*   cnt       = (int*)alloc((size_t)NN * 4);
  int*   row_start = (int*)alloc((size_t)(NN + 1) * 4);
  int*   cursor    = (int*)alloc((size_t)NN * 4);
  int*   es        = (int*)alloc((size_t)EE * 4);
  float* ew        = (float*)alloc((size_t)EE * 4);
  int*   et2       = (int*)alloc((size_t)EE * 4);

  hipLaunchKernelGGL(k_transpose, dim3(NTILE, B_ * T_), dim3(256), 0, stream, x, xT);
  hipLaunchKernelGGL(k_pack_conv_w, dim3(12), dim3(256), 0, stream, Wconv, wpkc);
  hipLaunchKernelGGL(k_conv_glu, dim3(MTILE, BT), dim3(256), 0, stream,
                     xT, (const short8*)wpkc, bconv, Xn);

  for (int g = 0; g < 2; ++g) {
    const int*   gsrc = g ? tg_src : hg_src;
    const int*   gdst = g ? tg_dst : hg_dst;
    const int*   gety = g ? tg_ety : hg_ety;
    const float* gw   = g ? tg_w : hg_w;
    const float* W    = g ? Wt : Wh;
    const float* bias = g ? bt_ : bh;
    int NE = g ? 2 : 3;
    int choff = g ? 64 : 0;

    hipMemsetAsync(cnt, 0, (size_t)NN * 4, stream);
    hipLaunchKernelGGL(k_count, dim3((EE + 255) / 256), dim3(256), 0, stream, gdst, cnt);
    hipLaunchKernelGGL(k_scan, dim3(1), dim3(1024), 0, stream, cnt, row_start, cursor);
    hipLaunchKernelGGL(k_scatter, dim3((EE + 255) / 256), dim3(256), 0, stream,
                       gsrc, gdst, gety, gw, cursor, es, ew, et2);

    BPtrs in1; BOut o1;
    for (int e = 0; e < 3; ++e) { in1.p[e] = Xn; o1.p[e] = zbase + (size_t)(2 * e) * ZN; }
    if (NE == 3)
      hipLaunchKernelGGL(k_spmm<3>, dim3(NN, 5), dim3(128), 0, stream, in1, o1, row_start, es, ew, et2);
    else
      hipLaunchKernelGGL(k_spmm<2>, dim3(NN, 5), dim3(128), 0, stream, in1, o1, row_start, es, ew, et2);

    BPtrs in2; BOut o2;
    for (int e = 0; e < 3; ++e) {
      in2.p[e] = zbase + (size_t)(2 * e) * ZN;
      o2.p[e]  = zbase + (size_t)(2 * e + 1) * ZN;
    }
    if (NE == 3)
      hipLaunchKernelGGL(k_spmm<3>, dim3(NN, 5), dim3(128), 0, stream, in2, o2, row_start, es, ew, et2);
    else
      hipLaunchKernelGGL(k_spmm<2>, dim3(NN, 5), dim3(128), 0, stream, in2, o2, row_start, es, ew, et2);

    int total = (1 + 2 * NE) * 2 * 4 * 64;
    hipLaunchKernelGGL(k_pack_gemm_w, dim3((total + 255) / 256), dim3(256), 0, stream, W, wpkg, NE);

    ZPtrs zs;
    zs.p[0] = Xn;
    for (int k = 1; k < 7; ++k) zs.p[k] = zbase + (size_t)(k - 1) * ZN;
    if (NE == 3)
      hipLaunchKernelGGL(k_gemm<7>, dim3(MTILE, BT), dim3(256), 0, stream,
                         zs, (const short8*)wpkg, bias, out, choff);
    else
      hipLaunchKernelGGL(k_gemm<5>, dim3(MTILE, BT), dim3(256), 0, stream,
                         zs, (const short8*)wpkg, bias, out, choff);
  }
}